// Round 3
// baseline (1863.530 us; speedup 1.0000x reference)
//
#include <hip/hip_runtime.h>

#define N_HP 49152
#define N_DST 50000
#define NE 400000
#define H 64
#define HID 128

#define SCAN_BLK 1024                     // elements per scan block
#define NBLK_TT ((N_DST + SCAN_BLK - 1) / SCAN_BLK)   // 49
#define NPART (4 * NBLK_TT)                            // 196

// ---------------- histogram + per-edge bucket rank (int4-vectorized) ----------
__global__ __launch_bounds__(256) void k_hist(const int* __restrict__ src_idx,
                                              const int* __restrict__ dst_idx,
                                              int* __restrict__ cnt_src,
                                              int* __restrict__ cnt_dst,
                                              int* __restrict__ pos) {
    int i4 = blockIdx.x * 256 + threadIdx.x;      // 4*NE/4 = 400000 int4s
    if (i4 >= NE) return;
    int tt = i4 / (NE / 4);
    int4 s = ((const int4*)src_idx)[i4];
    int4 d = ((const int4*)dst_idx)[i4];
    int* cs = cnt_src + tt * N_HP;
    int* cd = cnt_dst + tt * N_DST;
    atomicAdd(&cs[s.x], 1); atomicAdd(&cs[s.y], 1);
    atomicAdd(&cs[s.z], 1); atomicAdd(&cs[s.w], 1);
    int4 p;
    p.x = atomicAdd(&cd[d.x], 1);
    p.y = atomicAdd(&cd[d.y], 1);
    p.z = atomicAdd(&cd[d.z], 1);
    p.w = atomicAdd(&cd[d.w], 1);
    ((int4*)pos)[i4] = p;
}

__global__ __launch_bounds__(256) void k_rsout(const int* __restrict__ cnt_src,
                                               float* __restrict__ rs_out) {
    int i = blockIdx.x * 256 + threadIdx.x;
    if (i >= 4 * N_HP) return;
    int c = cnt_src[i];
    rs_out[i] = rsqrtf((float)(c > 1 ? c : 1));
}

// ---------------- parallel 3-phase exclusive scan of cnt_dst per tt ------------
__global__ __launch_bounds__(256) void k_scanA(const int* __restrict__ cnt,
                                               int* __restrict__ part) {
    int b = blockIdx.x, tt = b / NBLK_TT, blk = b % NBLK_TT;
    int el = blk * SCAN_BLK + threadIdx.x * 4;
    int4 v = make_int4(0, 0, 0, 0);
    if (el < N_DST) v = *(const int4*)&cnt[tt * N_DST + el];
    int s = v.x + v.y + v.z + v.w;
    for (int o = 32; o; o >>= 1) s += __shfl_xor(s, o);
    __shared__ int ws[4];
    if ((threadIdx.x & 63) == 0) ws[threadIdx.x >> 6] = s;
    __syncthreads();
    if (threadIdx.x == 0) part[b] = ws[0] + ws[1] + ws[2] + ws[3];
}

__global__ __launch_bounds__(256) void k_scanB(int* __restrict__ part) {
    __shared__ int sh[256];
    int t = threadIdx.x;
    int v = (t < NPART) ? part[t] : 0;
    sh[t] = v;
    __syncthreads();
    for (int o = 1; o < 256; o <<= 1) {
        int a = (t >= o) ? sh[t - o] : 0;
        __syncthreads();
        sh[t] += a;
        __syncthreads();
    }
    if (t < NPART) {
        int tt = t / NBLK_TT;
        int seg = (tt > 0) ? sh[tt * NBLK_TT - 1] : 0;
        part[t] = sh[t] - v - seg;    // exclusive within tt segment
    }
}

__global__ __launch_bounds__(256) void k_scanC(const int* __restrict__ cnt,
                                               const int* __restrict__ part,
                                               int* __restrict__ offs,
                                               float* __restrict__ rs_in) {
    int b = blockIdx.x, tt = b / NBLK_TT, blk = b % NBLK_TT;
    int el = blk * SCAN_BLK + threadIdx.x * 4;
    int4 v = make_int4(0, 0, 0, 0);
    bool ok = el < N_DST;
    if (ok) v = *(const int4*)&cnt[tt * N_DST + el];
    int s = v.x + v.y + v.z + v.w;
    __shared__ int sh[256];
    sh[threadIdx.x] = s;
    __syncthreads();
    for (int o = 1; o < 256; o <<= 1) {
        int a = (threadIdx.x >= o) ? sh[threadIdx.x - o] : 0;
        __syncthreads();
        sh[threadIdx.x] += a;
        __syncthreads();
    }
    if (ok) {
        int base = part[b] + sh[threadIdx.x] - s;   // exclusive
        int4 o4;
        o4.x = base;
        o4.y = base + v.x;
        o4.z = base + v.x + v.y;
        o4.w = base + v.x + v.y + v.z;
        *(int4*)&offs[tt * N_DST + el] = o4;
        float4 r;
        r.x = rsqrtf((float)(v.x > 1 ? v.x : 1));
        r.y = rsqrtf((float)(v.y > 1 ? v.y : 1));
        r.z = rsqrtf((float)(v.z > 1 ? v.z : 1));
        r.w = rsqrtf((float)(v.w > 1 ? v.w : 1));
        *(float4*)&rs_in[tt * N_DST + el] = r;
    }
}

// ---------------- CSR fill: no atomics (rank precomputed in k_hist) ------------
__global__ __launch_bounds__(256) void k_fill(const int* __restrict__ src_idx,
                                              const int* __restrict__ dst_idx,
                                              const int* __restrict__ pos,
                                              const int* __restrict__ offs,
                                              int* __restrict__ esrc) {
    int i4 = blockIdx.x * 256 + threadIdx.x;
    if (i4 >= NE) return;
    int tt = i4 / (NE / 4);
    int4 s = ((const int4*)src_idx)[i4];
    int4 d = ((const int4*)dst_idx)[i4];
    int4 p = ((const int4*)pos)[i4];
    const int* o = offs + tt * N_DST;
    int* e = esrc + tt * NE;
    e[o[d.x] + p.x] = s.x;
    e[o[d.y] + p.y] = s.y;
    e[o[d.z] + p.z] = s.z;
    e[o[d.w] + p.w] = s.w;
}

// ---------------- attention precompute: collapse the prev-dependent path ------
__global__ __launch_bounds__(128) void k_pre(const float* __restrict__ lin_W,
                                             const float* __restrict__ lin_b,
                                             const float* __restrict__ W1,
                                             const float* __restrict__ b1,
                                             const float* __restrict__ dec_W,
                                             float* __restrict__ attc) {
    int j = threadIdx.x;
    float c1 = 0.f, c0 = 0.f;
    for (int h = 0; h < H; ++h) {
        c1 += lin_W[h] * W1[h * HID + j];
        c0 += lin_b[h] * W1[h * HID + j];
    }
    attc[j] = c1;
    attc[HID + j] = c0 + b1[j];
    if (j == 0) {
        float e1 = 0.f, e0 = 0.f;
        for (int h = 0; h < H; ++h) { e1 += lin_W[h] * dec_W[h]; e0 += lin_b[h] * dec_W[h]; }
        attc[2 * HID] = e1;
        attc[2 * HID + 1] = e0;
    }
}

// ---------------- gather + conv + leaky (all 4 t), one wave per dst ------------
// No block barriers: agg is per-wave (wave-lockstep + compiler lgkmcnt).
__global__ __launch_bounds__(256) void k_gather(
    const float* __restrict__ x, const int* __restrict__ esrc,
    const int* __restrict__ offs, const int* __restrict__ cnt_dst,
    const float* __restrict__ rs_out, const float* __restrict__ rs_in,
    const float* __restrict__ conv_W, const float* __restrict__ conv_b,
    float* __restrict__ space1) {
    const int wave = threadIdx.x >> 6, lane = threadIdx.x & 63;
    const int dst = blockIdx.x * 4 + wave;   // grid exact: N_DST/4
    const int t_l = lane >> 4;
    const int h0 = (lane & 15) << 2;
    __shared__ float agg[4][4][H];           // [wave][t][h] — proven conflict-free
    float sp0 = 0.f, sp1 = 0.f, sp2 = 0.f, sp3 = 0.f;
    const float4* x4 = (const float4*)x;     // x row = 64 float4 (t = c>>4, h = (c&15)*4+i)

    for (int tt = 0; tt < 4; ++tt) {
        const int off = offs[tt * N_DST + dst];
        const int n = cnt_dst[tt * N_DST + dst];
        const int* ep = esrc + tt * NE + off;
        const float* rso = rs_out + tt * N_HP;
        float4 a0 = make_float4(0.f, 0.f, 0.f, 0.f);
        float4 a1 = make_float4(0.f, 0.f, 0.f, 0.f);
        float4 a2 = make_float4(0.f, 0.f, 0.f, 0.f);
        float4 a3 = make_float4(0.f, 0.f, 0.f, 0.f);
        int e = 0;
        for (; e + 4 <= n; e += 4) {   // 4 rows in flight
            int s0 = ep[e], s1 = ep[e + 1], s2 = ep[e + 2], s3 = ep[e + 3];
            float r0 = rso[s0], r1 = rso[s1], r2 = rso[s2], r3 = rso[s3];
            float4 v0 = x4[s0 * 64 + lane];
            float4 v1 = x4[s1 * 64 + lane];
            float4 v2 = x4[s2 * 64 + lane];
            float4 v3 = x4[s3 * 64 + lane];
            a0.x += v0.x * r0; a0.y += v0.y * r0; a0.z += v0.z * r0; a0.w += v0.w * r0;
            a1.x += v1.x * r1; a1.y += v1.y * r1; a1.z += v1.z * r1; a1.w += v1.w * r1;
            a2.x += v2.x * r2; a2.y += v2.y * r2; a2.z += v2.z * r2; a2.w += v2.w * r2;
            a3.x += v3.x * r3; a3.y += v3.y * r3; a3.z += v3.z * r3; a3.w += v3.w * r3;
        }
        for (; e < n; ++e) {
            int s0 = ep[e];
            float r0 = rso[s0];
            float4 v0 = x4[s0 * 64 + lane];
            a0.x += v0.x * r0; a0.y += v0.y * r0; a0.z += v0.z * r0; a0.w += v0.w * r0;
        }
        float ri = rs_in[tt * N_DST + dst];
        float4 acc = make_float4((a0.x + a1.x + a2.x + a3.x) * ri,
                                 (a0.y + a1.y + a2.y + a3.y) * ri,
                                 (a0.z + a1.z + a2.z + a3.z) * ri,
                                 (a0.w + a1.w + a2.w + a3.w) * ri);
        *(float4*)&agg[wave][t_l][h0] = acc;   // contiguous 1KB/wave: 0 conflicts
        const float* W = conv_W + tt * H * H;
        float m0 = 0.f, m1 = 0.f, m2 = 0.f, m3 = 0.f;
#pragma unroll
        for (int hc = 0; hc < H; hc += 4) {
            float4 q0 = *(const float4*)&agg[wave][0][hc];   // broadcast reads
            float4 q1 = *(const float4*)&agg[wave][1][hc];
            float4 q2 = *(const float4*)&agg[wave][2][hc];
            float4 q3 = *(const float4*)&agg[wave][3][hc];
            float w0 = W[(hc + 0) * H + lane];
            float w1 = W[(hc + 1) * H + lane];
            float w2 = W[(hc + 2) * H + lane];
            float w3 = W[(hc + 3) * H + lane];
            m0 += q0.x * w0 + q0.y * w1 + q0.z * w2 + q0.w * w3;
            m1 += q1.x * w0 + q1.y * w1 + q1.z * w2 + q1.w * w3;
            m2 += q2.x * w0 + q2.y * w1 + q2.z * w2 + q2.w * w3;
            m3 += q3.x * w0 + q3.y * w1 + q3.z * w2 + q3.w * w3;
        }
        float b = conv_b[tt * H + lane];
        m0 += b; m1 += b; m2 += b; m3 += b;
        sp0 += m0 > 0.f ? m0 : 0.01f * m0;
        sp1 += m1 > 0.f ? m1 : 0.01f * m1;
        sp2 += m2 > 0.f ? m2 : 0.01f * m2;
        sp3 += m3 > 0.f ? m3 : 0.01f * m3;
    }
    space1[(0 * N_DST + dst) * H + lane] = sp0;
    space1[(1 * N_DST + dst) * H + lane] = sp1;
    space1[(2 * N_DST + dst) * H + lane] = sp2;
    space1[(3 * N_DST + dst) * H + lane] = sp3;
}

// ---------------- attention + decode, all 4 t, 4 nodes per wave ----------------
#define SWS (H + 1)   // 65: stride-padded transposed W1 -> conflict-free
__global__ __launch_bounds__(512) void k_att(
    const float* __restrict__ sp, const float* __restrict__ prev0,
    const float* __restrict__ W1, const float* __restrict__ b1,
    const float* __restrict__ W2, const float* __restrict__ b2,
    const float* __restrict__ dec_W, const float* __restrict__ dec_b,
    const float* __restrict__ attc,
    float* __restrict__ out) {
    __shared__ float sW[HID * SWS];       // sW[j*65+h] = W1[h][j]
    __shared__ float sb[8][4][H];
    const int wave = threadIdx.x >> 6, lane = threadIdx.x & 63;
    const int n0 = (blockIdx.x * 8 + wave) * 4;   // 4 nodes per wave
    for (int i = threadIdx.x; i < H * HID; i += 512) {
        int h = i >> 7, j = i & 127;               // coalesced W1 read
        sW[j * SWS + h] = W1[i];
    }
    __syncthreads();   // only block-wide barrier

    const float b1a = b1[lane], b1b = b1[lane + 64];
    const float w2a = W2[lane], w2b = W2[lane + 64];
    const float c1a = attc[lane], c1b = attc[lane + 64];
    const float c0a = attc[HID + lane], c0b = attc[HID + lane + 64];
    const float e1s = attc[2 * HID], e0s = attc[2 * HID + 1];
    const float decw = dec_W[lane];
    const float b2s = b2[0], decb = dec_b[0];

    float s1v[4][4];   // [k][t]
    float prev[4];
#pragma unroll
    for (int k = 0; k < 4; ++k) {
        int nk = n0 + k; if (nk >= N_DST) nk = 0;
        prev[k] = prev0[nk];
#pragma unroll
        for (int t = 0; t < 4; ++t)
            s1v[k][t] = sp[((size_t)t * N_DST + nk) * H + lane];
    }

    const float* sWa = &sW[lane * SWS];
    const float* sWb = &sW[(lane + 64) * SWS];
#pragma unroll
    for (int t = 0; t < 4; ++t) {
        sb[wave][0][lane] = s1v[0][t];
        sb[wave][1][lane] = s1v[1][t];
        sb[wave][2][lane] = s1v[2][t];
        sb[wave][3][lane] = s1v[3][t];
        float d0[4] = {0.f, 0.f, 0.f, 0.f};
        float d1[4] = {0.f, 0.f, 0.f, 0.f};
#pragma unroll
        for (int hc = 0; hc < H; hc += 4) {
            float wa0 = sWa[hc], wa1 = sWa[hc + 1], wa2 = sWa[hc + 2], wa3 = sWa[hc + 3];
            float wb0 = sWb[hc], wb1 = sWb[hc + 1], wb2 = sWb[hc + 2], wb3 = sWb[hc + 3];
#pragma unroll
            for (int k = 0; k < 4; ++k) {
                float4 sv = *(const float4*)&sb[wave][k][hc];   // broadcast
                d0[k] += sv.x * wa0 + sv.y * wa1 + sv.z * wa2 + sv.w * wa3;
                d1[k] += sv.x * wb0 + sv.y * wb1 + sv.z * wb2 + sv.w * wb3;
            }
        }
        float p0[4], p1[4], p2[4];
#pragma unroll
        for (int k = 0; k < 4; ++k) {
            p0[k] = tanhf(d0[k] + b1a) * w2a + tanhf(d1[k] + b1b) * w2b;
            p1[k] = tanhf(prev[k] * c1a + c0a) * w2a + tanhf(prev[k] * c1b + c0b) * w2b;
            p2[k] = s1v[k][t] * decw;
        }
        for (int o = 32; o; o >>= 1) {
#pragma unroll
            for (int k = 0; k < 4; ++k) {
                p0[k] += __shfl_xor(p0[k], o);
                p1[k] += __shfl_xor(p1[k], o);
                p2[k] += __shfl_xor(p2[k], o);
            }
        }
#pragma unroll
        for (int k = 0; k < 4; ++k) {
            float l0 = p0[k] + b2s, l1 = p1[k] + b2s;
            float mx = fmaxf(l0, l1);
            float ea = expf(l0 - mx), eb = expf(l1 - mx);
            float inv = 1.f / (ea + eb);
            float s2d = prev[k] * e1s + e0s;
            float ov = (ea * p2[k] + eb * s2d) * inv + decb;
            prev[k] = ov;
            if (lane == 0 && n0 + k < N_DST) out[t * N_DST + n0 + k] = ov;
        }
    }
}

extern "C" void kernel_launch(void* const* d_in, const int* in_sizes, int n_in,
                              void* d_out, int out_size, void* d_ws, size_t ws_size,
                              hipStream_t stream) {
    const float* x      = (const float*)d_in[0];
    const float* prev0  = (const float*)d_in[1];
    const float* conv_W = (const float*)d_in[2];
    const float* conv_b = (const float*)d_in[3];
    const float* lin_W  = (const float*)d_in[4];
    const float* lin_b  = (const float*)d_in[5];
    const float* att_W1 = (const float*)d_in[6];
    const float* att_b1 = (const float*)d_in[7];
    const float* att_W2 = (const float*)d_in[8];
    const float* att_b2 = (const float*)d_in[9];
    const float* dec_W  = (const float*)d_in[10];
    const float* dec_b  = (const float*)d_in[11];
    const int* src_idx  = (const int*)d_in[12];
    const int* dst_idx  = (const int*)d_in[13];
    float* out = (float*)d_out;

    char* p = (char*)d_ws;
    auto alloc = [&](size_t bytes) {
        char* q = p;
        p += (bytes + 255) & ~(size_t)255;
        return q;
    };
    int*   cnt_src = (int*)alloc((size_t)4 * N_HP * 4);
    int*   cnt_dst = (int*)alloc((size_t)4 * N_DST * 4);
    int*   offs    = (int*)alloc((size_t)4 * N_DST * 4);
    float* rs_out  = (float*)alloc((size_t)4 * N_HP * 4);
    float* rs_in   = (float*)alloc((size_t)4 * N_DST * 4);
    int*   pos     = (int*)alloc((size_t)4 * NE * 4);
    int*   esrc    = (int*)alloc((size_t)4 * NE * 4);
    int*   part    = (int*)alloc((size_t)NPART * 4);
    float* attc    = (float*)alloc((size_t)(2 * HID + 2) * 4);
    float* space1  = (float*)alloc((size_t)4 * N_DST * H * 4);

    // zero cnt_src + cnt_dst (contiguous, 256-aligned sizes)
    hipMemsetAsync(cnt_src, 0, (size_t)((char*)offs - (char*)cnt_src), stream);

    k_hist<<<(NE + 255) / 256, 256, 0, stream>>>(src_idx, dst_idx, cnt_src, cnt_dst, pos);
    k_rsout<<<(4 * N_HP + 255) / 256, 256, 0, stream>>>(cnt_src, rs_out);
    k_scanA<<<NPART, 256, 0, stream>>>(cnt_dst, part);
    k_scanB<<<1, 256, 0, stream>>>(part);
    k_scanC<<<NPART, 256, 0, stream>>>(cnt_dst, part, offs, rs_in);
    k_fill<<<(NE + 255) / 256, 256, 0, stream>>>(src_idx, dst_idx, pos, offs, esrc);
    k_pre<<<1, 128, 0, stream>>>(lin_W, lin_b, att_W1, att_b1, dec_W, attc);
    k_gather<<<N_DST / 4, 256, 0, stream>>>(x, esrc, offs, cnt_dst, rs_out, rs_in,
                                            conv_W, conv_b, space1);
    k_att<<<(N_DST + 31) / 32, 512, 0, stream>>>(space1, prev0,
                                                 att_W1, att_b1, att_W2, att_b2,
                                                 dec_W, dec_b, attc, out);
}

// Round 4
// 1834.218 us; speedup vs baseline: 1.0160x; 1.0160x over previous
//
#include <hip/hip_runtime.h>

#define N_HP 49152
#define N_DST 50000
#define NE 400000
#define H 64
#define HID 128

#define SCAN_BLK 1024                     // elements per scan block
#define NBLK_TT ((N_DST + SCAN_BLK - 1) / SCAN_BLK)   // 49
#define NPART (4 * NBLK_TT)                            // 196

// ---------------- histogram + per-edge bucket rank (int4-vectorized) ----------
__global__ __launch_bounds__(256) void k_hist(const int* __restrict__ src_idx,
                                              const int* __restrict__ dst_idx,
                                              int* __restrict__ cnt_src,
                                              int* __restrict__ cnt_dst,
                                              int* __restrict__ pos) {
    int i4 = blockIdx.x * 256 + threadIdx.x;      // 4*NE/4 = 400000 int4s
    if (i4 >= NE) return;
    int tt = i4 / (NE / 4);
    int4 s = ((const int4*)src_idx)[i4];
    int4 d = ((const int4*)dst_idx)[i4];
    int* cs = cnt_src + tt * N_HP;
    int* cd = cnt_dst + tt * N_DST;
    atomicAdd(&cs[s.x], 1); atomicAdd(&cs[s.y], 1);
    atomicAdd(&cs[s.z], 1); atomicAdd(&cs[s.w], 1);
    int4 p;
    p.x = atomicAdd(&cd[d.x], 1);
    p.y = atomicAdd(&cd[d.y], 1);
    p.z = atomicAdd(&cd[d.z], 1);
    p.w = atomicAdd(&cd[d.w], 1);
    ((int4*)pos)[i4] = p;
}

__global__ __launch_bounds__(256) void k_rsout(const int* __restrict__ cnt_src,
                                               float* __restrict__ rs_out) {
    int i = blockIdx.x * 256 + threadIdx.x;
    if (i >= 4 * N_HP) return;
    int c = cnt_src[i];
    rs_out[i] = rsqrtf((float)(c > 1 ? c : 1));
}

// ---------------- parallel 3-phase exclusive scan of cnt_dst per tt ------------
__global__ __launch_bounds__(256) void k_scanA(const int* __restrict__ cnt,
                                               int* __restrict__ part) {
    int b = blockIdx.x, tt = b / NBLK_TT, blk = b % NBLK_TT;
    int el = blk * SCAN_BLK + threadIdx.x * 4;
    int4 v = make_int4(0, 0, 0, 0);
    if (el < N_DST) v = *(const int4*)&cnt[tt * N_DST + el];
    int s = v.x + v.y + v.z + v.w;
    for (int o = 32; o; o >>= 1) s += __shfl_xor(s, o);
    __shared__ int ws[4];
    if ((threadIdx.x & 63) == 0) ws[threadIdx.x >> 6] = s;
    __syncthreads();
    if (threadIdx.x == 0) part[b] = ws[0] + ws[1] + ws[2] + ws[3];
}

__global__ __launch_bounds__(256) void k_scanB(int* __restrict__ part) {
    __shared__ int sh[256];
    int t = threadIdx.x;
    int v = (t < NPART) ? part[t] : 0;
    sh[t] = v;
    __syncthreads();
    for (int o = 1; o < 256; o <<= 1) {
        int a = (t >= o) ? sh[t - o] : 0;
        __syncthreads();
        sh[t] += a;
        __syncthreads();
    }
    if (t < NPART) {
        int tt = t / NBLK_TT;
        int seg = (tt > 0) ? sh[tt * NBLK_TT - 1] : 0;
        part[t] = sh[t] - v - seg;    // exclusive within tt segment
    }
}

__global__ __launch_bounds__(256) void k_scanC(const int* __restrict__ cnt,
                                               const int* __restrict__ part,
                                               int* __restrict__ offs,
                                               float* __restrict__ rs_in) {
    int b = blockIdx.x, tt = b / NBLK_TT, blk = b % NBLK_TT;
    int el = blk * SCAN_BLK + threadIdx.x * 4;
    int4 v = make_int4(0, 0, 0, 0);
    bool ok = el < N_DST;
    if (ok) v = *(const int4*)&cnt[tt * N_DST + el];
    int s = v.x + v.y + v.z + v.w;
    __shared__ int sh[256];
    sh[threadIdx.x] = s;
    __syncthreads();
    for (int o = 1; o < 256; o <<= 1) {
        int a = (threadIdx.x >= o) ? sh[threadIdx.x - o] : 0;
        __syncthreads();
        sh[threadIdx.x] += a;
        __syncthreads();
    }
    if (ok) {
        int base = part[b] + sh[threadIdx.x] - s;   // exclusive
        int4 o4;
        o4.x = base;
        o4.y = base + v.x;
        o4.z = base + v.x + v.y;
        o4.w = base + v.x + v.y + v.z;
        *(int4*)&offs[tt * N_DST + el] = o4;
        float4 r;
        r.x = rsqrtf((float)(v.x > 1 ? v.x : 1));
        r.y = rsqrtf((float)(v.y > 1 ? v.y : 1));
        r.z = rsqrtf((float)(v.z > 1 ? v.z : 1));
        r.w = rsqrtf((float)(v.w > 1 ? v.w : 1));
        *(float4*)&rs_in[tt * N_DST + el] = r;
    }
}

// ---------------- CSR fill: no atomics (rank precomputed in k_hist) ------------
__global__ __launch_bounds__(256) void k_fill(const int* __restrict__ src_idx,
                                              const int* __restrict__ dst_idx,
                                              const int* __restrict__ pos,
                                              const int* __restrict__ offs,
                                              int* __restrict__ esrc) {
    int i4 = blockIdx.x * 256 + threadIdx.x;
    if (i4 >= NE) return;
    int tt = i4 / (NE / 4);
    int4 s = ((const int4*)src_idx)[i4];
    int4 d = ((const int4*)dst_idx)[i4];
    int4 p = ((const int4*)pos)[i4];
    const int* o = offs + tt * N_DST;
    int* e = esrc + tt * NE;
    e[o[d.x] + p.x] = s.x;
    e[o[d.y] + p.y] = s.y;
    e[o[d.z] + p.z] = s.z;
    e[o[d.w] + p.w] = s.w;
}

// ---------------- attention precompute: collapse the prev-dependent path ------
__global__ __launch_bounds__(128) void k_pre(const float* __restrict__ lin_W,
                                             const float* __restrict__ lin_b,
                                             const float* __restrict__ W1,
                                             const float* __restrict__ b1,
                                             const float* __restrict__ dec_W,
                                             float* __restrict__ attc) {
    int j = threadIdx.x;
    float c1 = 0.f, c0 = 0.f;
    for (int h = 0; h < H; ++h) {
        c1 += lin_W[h] * W1[h * HID + j];
        c0 += lin_b[h] * W1[h * HID + j];
    }
    attc[j] = c1;
    attc[HID + j] = c0 + b1[j];
    if (j == 0) {
        float e1 = 0.f, e0 = 0.f;
        for (int h = 0; h < H; ++h) { e1 += lin_W[h] * dec_W[h]; e0 += lin_b[h] * dec_W[h]; }
        attc[2 * HID] = e1;
        attc[2 * HID + 1] = e0;
    }
}

// ---------------- gather + conv + leaky (all 4 t), one wave per dst ------------
// No block barriers: agg is per-wave (wave-lockstep + compiler lgkmcnt).
__global__ __launch_bounds__(256) void k_gather(
    const float* __restrict__ x, const int* __restrict__ esrc,
    const int* __restrict__ offs, const int* __restrict__ cnt_dst,
    const float* __restrict__ rs_out, const float* __restrict__ rs_in,
    const float* __restrict__ conv_W, const float* __restrict__ conv_b,
    float* __restrict__ space1) {
    const int wave = threadIdx.x >> 6, lane = threadIdx.x & 63;
    const int dst = blockIdx.x * 4 + wave;   // grid exact: N_DST/4
    const int t_l = lane >> 4;
    const int h0 = (lane & 15) << 2;
    __shared__ float agg[4][4][H];           // [wave][t][h] — proven conflict-free
    float sp0 = 0.f, sp1 = 0.f, sp2 = 0.f, sp3 = 0.f;
    const float4* x4 = (const float4*)x;     // x row = 64 float4 (t = c>>4, h = (c&15)*4+i)

    for (int tt = 0; tt < 4; ++tt) {
        const int off = offs[tt * N_DST + dst];
        const int n = cnt_dst[tt * N_DST + dst];
        const int* ep = esrc + tt * NE + off;
        const float* rso = rs_out + tt * N_HP;
        float4 a0 = make_float4(0.f, 0.f, 0.f, 0.f);
        float4 a1 = make_float4(0.f, 0.f, 0.f, 0.f);
        float4 a2 = make_float4(0.f, 0.f, 0.f, 0.f);
        float4 a3 = make_float4(0.f, 0.f, 0.f, 0.f);
        int e = 0;
        for (; e + 8 <= n; e += 8) {   // 8 rows in flight
            int s0 = ep[e],     s1 = ep[e + 1], s2 = ep[e + 2], s3 = ep[e + 3];
            int s4 = ep[e + 4], s5 = ep[e + 5], s6 = ep[e + 6], s7 = ep[e + 7];
            float r0 = rso[s0], r1 = rso[s1], r2 = rso[s2], r3 = rso[s3];
            float r4 = rso[s4], r5 = rso[s5], r6 = rso[s6], r7 = rso[s7];
            float4 v0 = x4[s0 * 64 + lane];
            float4 v1 = x4[s1 * 64 + lane];
            float4 v2 = x4[s2 * 64 + lane];
            float4 v3 = x4[s3 * 64 + lane];
            float4 v4 = x4[s4 * 64 + lane];
            float4 v5 = x4[s5 * 64 + lane];
            float4 v6 = x4[s6 * 64 + lane];
            float4 v7 = x4[s7 * 64 + lane];
            a0.x += v0.x * r0; a0.y += v0.y * r0; a0.z += v0.z * r0; a0.w += v0.w * r0;
            a1.x += v1.x * r1; a1.y += v1.y * r1; a1.z += v1.z * r1; a1.w += v1.w * r1;
            a2.x += v2.x * r2; a2.y += v2.y * r2; a2.z += v2.z * r2; a2.w += v2.w * r2;
            a3.x += v3.x * r3; a3.y += v3.y * r3; a3.z += v3.z * r3; a3.w += v3.w * r3;
            a0.x += v4.x * r4; a0.y += v4.y * r4; a0.z += v4.z * r4; a0.w += v4.w * r4;
            a1.x += v5.x * r5; a1.y += v5.y * r5; a1.z += v5.z * r5; a1.w += v5.w * r5;
            a2.x += v6.x * r6; a2.y += v6.y * r6; a2.z += v6.z * r6; a2.w += v6.w * r6;
            a3.x += v7.x * r7; a3.y += v7.y * r7; a3.z += v7.z * r7; a3.w += v7.w * r7;
        }
        for (; e + 2 <= n; e += 2) {
            int s0 = ep[e], s1 = ep[e + 1];
            float r0 = rso[s0], r1 = rso[s1];
            float4 v0 = x4[s0 * 64 + lane];
            float4 v1 = x4[s1 * 64 + lane];
            a0.x += v0.x * r0; a0.y += v0.y * r0; a0.z += v0.z * r0; a0.w += v0.w * r0;
            a1.x += v1.x * r1; a1.y += v1.y * r1; a1.z += v1.z * r1; a1.w += v1.w * r1;
        }
        if (e < n) {
            int s0 = ep[e];
            float r0 = rso[s0];
            float4 v0 = x4[s0 * 64 + lane];
            a0.x += v0.x * r0; a0.y += v0.y * r0; a0.z += v0.z * r0; a0.w += v0.w * r0;
        }
        float ri = rs_in[tt * N_DST + dst];
        float4 acc = make_float4((a0.x + a1.x + a2.x + a3.x) * ri,
                                 (a0.y + a1.y + a2.y + a3.y) * ri,
                                 (a0.z + a1.z + a2.z + a3.z) * ri,
                                 (a0.w + a1.w + a2.w + a3.w) * ri);
        *(float4*)&agg[wave][t_l][h0] = acc;   // contiguous 1KB/wave: 0 conflicts
        const float* W = conv_W + tt * H * H;
        float m0 = 0.f, m1 = 0.f, m2 = 0.f, m3 = 0.f;
#pragma unroll
        for (int hc = 0; hc < H; hc += 4) {
            float4 q0 = *(const float4*)&agg[wave][0][hc];   // broadcast reads
            float4 q1 = *(const float4*)&agg[wave][1][hc];
            float4 q2 = *(const float4*)&agg[wave][2][hc];
            float4 q3 = *(const float4*)&agg[wave][3][hc];
            float w0 = W[(hc + 0) * H + lane];
            float w1 = W[(hc + 1) * H + lane];
            float w2 = W[(hc + 2) * H + lane];
            float w3 = W[(hc + 3) * H + lane];
            m0 += q0.x * w0 + q0.y * w1 + q0.z * w2 + q0.w * w3;
            m1 += q1.x * w0 + q1.y * w1 + q1.z * w2 + q1.w * w3;
            m2 += q2.x * w0 + q2.y * w1 + q2.z * w2 + q2.w * w3;
            m3 += q3.x * w0 + q3.y * w1 + q3.z * w2 + q3.w * w3;
        }
        float b = conv_b[tt * H + lane];
        m0 += b; m1 += b; m2 += b; m3 += b;
        sp0 += m0 > 0.f ? m0 : 0.01f * m0;
        sp1 += m1 > 0.f ? m1 : 0.01f * m1;
        sp2 += m2 > 0.f ? m2 : 0.01f * m2;
        sp3 += m3 > 0.f ? m3 : 0.01f * m3;
    }
    space1[(0 * N_DST + dst) * H + lane] = sp0;
    space1[(1 * N_DST + dst) * H + lane] = sp1;
    space1[(2 * N_DST + dst) * H + lane] = sp2;
    space1[(3 * N_DST + dst) * H + lane] = sp3;
}

// ---------------- attention + decode, all 4 t, 4 nodes per wave ----------------
// NOTE: nothing is array-indexed by t (rule #20 — avoids scratch); s1 is
// re-loaded from global inside the (non-unrolled) t loop.
#define SWS (H + 1)   // 65: stride-padded transposed W1 -> conflict-free
__global__ __launch_bounds__(512) void k_att(
    const float* __restrict__ sp, const float* __restrict__ prev0,
    const float* __restrict__ W1, const float* __restrict__ b1,
    const float* __restrict__ W2, const float* __restrict__ b2,
    const float* __restrict__ dec_W, const float* __restrict__ dec_b,
    const float* __restrict__ attc,
    float* __restrict__ out) {
    __shared__ float sW[HID * SWS];       // sW[j*65+h] = W1[h][j], 33.3 KB
    __shared__ float sb[8][4][H];
    const int wave = threadIdx.x >> 6, lane = threadIdx.x & 63;
    const int n0 = (blockIdx.x * 8 + wave) * 4;   // 4 nodes per wave
    for (int i = threadIdx.x; i < H * HID; i += 512) {
        int h = i >> 7, j = i & 127;               // coalesced W1 read
        sW[j * SWS + h] = W1[i];
    }
    __syncthreads();   // only block-wide barrier

    const float b1a = b1[lane], b1b = b1[lane + 64];
    const float w2a = W2[lane], w2b = W2[lane + 64];
    const float c1a = attc[lane], c1b = attc[lane + 64];
    const float c0a = attc[HID + lane], c0b = attc[HID + lane + 64];
    const float e1s = attc[2 * HID], e0s = attc[2 * HID + 1];
    const float decw = dec_W[lane];
    const float b2s = b2[0], decb = dec_b[0];

    int nk[4];
    float prev[4];
#pragma unroll
    for (int k = 0; k < 4; ++k) {
        int n = n0 + k;
        nk[k] = n < N_DST ? n : N_DST - 1;
        prev[k] = prev0[nk[k]];
    }

    const float* sWa = &sW[lane * SWS];
    const float* sWb = &sW[(lane + 64) * SWS];
    for (int t = 0; t < 4; ++t) {        // serial chain; NOT unrolled
        const float* spt = sp + (size_t)t * N_DST * H;
        float s1v[4];
#pragma unroll
        for (int k = 0; k < 4; ++k) {
            s1v[k] = spt[(size_t)nk[k] * H + lane];   // coalesced 256B / node
            sb[wave][k][lane] = s1v[k];
        }
        float d0[4] = {0.f, 0.f, 0.f, 0.f};
        float d1[4] = {0.f, 0.f, 0.f, 0.f};
#pragma unroll
        for (int hc = 0; hc < H; hc += 4) {
            float wa0 = sWa[hc], wa1 = sWa[hc + 1], wa2 = sWa[hc + 2], wa3 = sWa[hc + 3];
            float wb0 = sWb[hc], wb1 = sWb[hc + 1], wb2 = sWb[hc + 2], wb3 = sWb[hc + 3];
#pragma unroll
            for (int k = 0; k < 4; ++k) {
                float4 sv = *(const float4*)&sb[wave][k][hc];   // broadcast
                d0[k] += sv.x * wa0 + sv.y * wa1 + sv.z * wa2 + sv.w * wa3;
                d1[k] += sv.x * wb0 + sv.y * wb1 + sv.z * wb2 + sv.w * wb3;
            }
        }
        float p0[4], p1[4], p2[4];
#pragma unroll
        for (int k = 0; k < 4; ++k) {
            p0[k] = tanhf(d0[k] + b1a) * w2a + tanhf(d1[k] + b1b) * w2b;
            p1[k] = tanhf(prev[k] * c1a + c0a) * w2a + tanhf(prev[k] * c1b + c0b) * w2b;
            p2[k] = s1v[k] * decw;
        }
        for (int o = 32; o; o >>= 1) {
#pragma unroll
            for (int k = 0; k < 4; ++k) {
                p0[k] += __shfl_xor(p0[k], o);
                p1[k] += __shfl_xor(p1[k], o);
                p2[k] += __shfl_xor(p2[k], o);
            }
        }
        float* outt = out + (size_t)t * N_DST;
#pragma unroll
        for (int k = 0; k < 4; ++k) {
            float l0 = p0[k] + b2s, l1 = p1[k] + b2s;
            float mx = fmaxf(l0, l1);
            float ea = expf(l0 - mx), eb = expf(l1 - mx);
            float inv = 1.f / (ea + eb);
            float s2d = prev[k] * e1s + e0s;
            float ov = (ea * p2[k] + eb * s2d) * inv + decb;
            prev[k] = ov;
            if (lane == 0 && n0 + k < N_DST) outt[n0 + k] = ov;
        }
    }
}

extern "C" void kernel_launch(void* const* d_in, const int* in_sizes, int n_in,
                              void* d_out, int out_size, void* d_ws, size_t ws_size,
                              hipStream_t stream) {
    const float* x      = (const float*)d_in[0];
    const float* prev0  = (const float*)d_in[1];
    const float* conv_W = (const float*)d_in[2];
    const float* conv_b = (const float*)d_in[3];
    const float* lin_W  = (const float*)d_in[4];
    const float* lin_b  = (const float*)d_in[5];
    const float* att_W1 = (const float*)d_in[6];
    const float* att_b1 = (const float*)d_in[7];
    const float* att_W2 = (const float*)d_in[8];
    const float* att_b2 = (const float*)d_in[9];
    const float* dec_W  = (const float*)d_in[10];
    const float* dec_b  = (const float*)d_in[11];
    const int* src_idx  = (const int*)d_in[12];
    const int* dst_idx  = (const int*)d_in[13];
    float* out = (float*)d_out;

    char* p = (char*)d_ws;
    auto alloc = [&](size_t bytes) {
        char* q = p;
        p += (bytes + 255) & ~(size_t)255;
        return q;
    };
    int*   cnt_src = (int*)alloc((size_t)4 * N_HP * 4);
    int*   cnt_dst = (int*)alloc((size_t)4 * N_DST * 4);
    int*   offs    = (int*)alloc((size_t)4 * N_DST * 4);
    float* rs_out  = (float*)alloc((size_t)4 * N_HP * 4);
    float* rs_in   = (float*)alloc((size_t)4 * N_DST * 4);
    int*   pos     = (int*)alloc((size_t)4 * NE * 4);
    int*   esrc    = (int*)alloc((size_t)4 * NE * 4);
    int*   part    = (int*)alloc((size_t)NPART * 4);
    float* attc    = (float*)alloc((size_t)(2 * HID + 2) * 4);
    float* space1  = (float*)alloc((size_t)4 * N_DST * H * 4);

    // zero cnt_src + cnt_dst (contiguous, 256-aligned sizes)
    hipMemsetAsync(cnt_src, 0, (size_t)((char*)offs - (char*)cnt_src), stream);

    k_hist<<<(NE + 255) / 256, 256, 0, stream>>>(src_idx, dst_idx, cnt_src, cnt_dst, pos);
    k_rsout<<<(4 * N_HP + 255) / 256, 256, 0, stream>>>(cnt_src, rs_out);
    k_scanA<<<NPART, 256, 0, stream>>>(cnt_dst, part);
    k_scanB<<<1, 256, 0, stream>>>(part);
    k_scanC<<<NPART, 256, 0, stream>>>(cnt_dst, part, offs, rs_in);
    k_fill<<<(NE + 255) / 256, 256, 0, stream>>>(src_idx, dst_idx, pos, offs, esrc);
    k_pre<<<1, 128, 0, stream>>>(lin_W, lin_b, att_W1, att_b1, dec_W, attc);
    k_gather<<<N_DST / 4, 256, 0, stream>>>(x, esrc, offs, cnt_dst, rs_out, rs_in,
                                            conv_W, conv_b, space1);
    k_att<<<(N_DST + 31) / 32, 512, 0, stream>>>(space1, prev0,
                                                 att_W1, att_b1, att_W2, att_b2,
                                                 dec_W, dec_b, attc, out);
}

// Round 5
// 623.231 us; speedup vs baseline: 2.9901x; 2.9431x over previous
//
#include <hip/hip_runtime.h>

#define N_HP 49152
#define N_DST 50000
#define NE 400000
#define H 64
#define HID 128

#define SCAN_BLK 1024                     // elements per scan block
#define NBLK_TT ((N_DST + SCAN_BLK - 1) / SCAN_BLK)   // 49
#define NPART (4 * NBLK_TT)                            // 196

// ---------------- histogram + per-edge bucket rank (int4-vectorized) ----------
__global__ __launch_bounds__(256) void k_hist(const int* __restrict__ src_idx,
                                              const int* __restrict__ dst_idx,
                                              int* __restrict__ cnt_src,
                                              int* __restrict__ cnt_dst,
                                              int* __restrict__ pos) {
    int i4 = blockIdx.x * 256 + threadIdx.x;      // 4*NE/4 = 400000 int4s
    if (i4 >= NE) return;
    int tt = i4 / (NE / 4);
    int4 s = ((const int4*)src_idx)[i4];
    int4 d = ((const int4*)dst_idx)[i4];
    int* cs = cnt_src + tt * N_HP;
    int* cd = cnt_dst + tt * N_DST;
    atomicAdd(&cs[s.x], 1); atomicAdd(&cs[s.y], 1);
    atomicAdd(&cs[s.z], 1); atomicAdd(&cs[s.w], 1);
    int4 p;
    p.x = atomicAdd(&cd[d.x], 1);
    p.y = atomicAdd(&cd[d.y], 1);
    p.z = atomicAdd(&cd[d.z], 1);
    p.w = atomicAdd(&cd[d.w], 1);
    ((int4*)pos)[i4] = p;
}

__global__ __launch_bounds__(256) void k_rsout(const int* __restrict__ cnt_src,
                                               float* __restrict__ rs_out) {
    int i = blockIdx.x * 256 + threadIdx.x;
    if (i >= 4 * N_HP) return;
    int c = cnt_src[i];
    rs_out[i] = rsqrtf((float)(c > 1 ? c : 1));
}

// ---------------- parallel 3-phase exclusive scan of cnt_dst per tt ------------
__global__ __launch_bounds__(256) void k_scanA(const int* __restrict__ cnt,
                                               int* __restrict__ part) {
    int b = blockIdx.x, tt = b / NBLK_TT, blk = b % NBLK_TT;
    int el = blk * SCAN_BLK + threadIdx.x * 4;
    int4 v = make_int4(0, 0, 0, 0);
    if (el < N_DST) v = *(const int4*)&cnt[tt * N_DST + el];
    int s = v.x + v.y + v.z + v.w;
    for (int o = 32; o; o >>= 1) s += __shfl_xor(s, o);
    __shared__ int ws[4];
    if ((threadIdx.x & 63) == 0) ws[threadIdx.x >> 6] = s;
    __syncthreads();
    if (threadIdx.x == 0) part[b] = ws[0] + ws[1] + ws[2] + ws[3];
}

__global__ __launch_bounds__(256) void k_scanB(int* __restrict__ part) {
    __shared__ int sh[256];
    int t = threadIdx.x;
    int v = (t < NPART) ? part[t] : 0;
    sh[t] = v;
    __syncthreads();
    for (int o = 1; o < 256; o <<= 1) {
        int a = (t >= o) ? sh[t - o] : 0;
        __syncthreads();
        sh[t] += a;
        __syncthreads();
    }
    if (t < NPART) {
        int tt = t / NBLK_TT;
        int seg = (tt > 0) ? sh[tt * NBLK_TT - 1] : 0;
        part[t] = sh[t] - v - seg;    // exclusive within tt segment
    }
}

__global__ __launch_bounds__(256) void k_scanC(const int* __restrict__ cnt,
                                               const int* __restrict__ part,
                                               int* __restrict__ offs,
                                               float* __restrict__ rs_in) {
    int b = blockIdx.x, tt = b / NBLK_TT, blk = b % NBLK_TT;
    int el = blk * SCAN_BLK + threadIdx.x * 4;
    int4 v = make_int4(0, 0, 0, 0);
    bool ok = el < N_DST;
    if (ok) v = *(const int4*)&cnt[tt * N_DST + el];
    int s = v.x + v.y + v.z + v.w;
    __shared__ int sh[256];
    sh[threadIdx.x] = s;
    __syncthreads();
    for (int o = 1; o < 256; o <<= 1) {
        int a = (threadIdx.x >= o) ? sh[threadIdx.x - o] : 0;
        __syncthreads();
        sh[threadIdx.x] += a;
        __syncthreads();
    }
    if (ok) {
        int base = part[b] + sh[threadIdx.x] - s;   // exclusive
        int4 o4;
        o4.x = base;
        o4.y = base + v.x;
        o4.z = base + v.x + v.y;
        o4.w = base + v.x + v.y + v.z;
        *(int4*)&offs[tt * N_DST + el] = o4;
        float4 r;
        r.x = rsqrtf((float)(v.x > 1 ? v.x : 1));
        r.y = rsqrtf((float)(v.y > 1 ? v.y : 1));
        r.z = rsqrtf((float)(v.z > 1 ? v.z : 1));
        r.w = rsqrtf((float)(v.w > 1 ? v.w : 1));
        *(float4*)&rs_in[tt * N_DST + el] = r;
    }
}

// ---------------- CSR fill: no atomics (rank precomputed in k_hist) ------------
__global__ __launch_bounds__(256) void k_fill(const int* __restrict__ src_idx,
                                              const int* __restrict__ dst_idx,
                                              const int* __restrict__ pos,
                                              const int* __restrict__ offs,
                                              int* __restrict__ esrc) {
    int i4 = blockIdx.x * 256 + threadIdx.x;
    if (i4 >= NE) return;
    int tt = i4 / (NE / 4);
    int4 s = ((const int4*)src_idx)[i4];
    int4 d = ((const int4*)dst_idx)[i4];
    int4 p = ((const int4*)pos)[i4];
    const int* o = offs + tt * N_DST;
    int* e = esrc + tt * NE;
    e[o[d.x] + p.x] = s.x;
    e[o[d.y] + p.y] = s.y;
    e[o[d.z] + p.z] = s.z;
    e[o[d.w] + p.w] = s.w;
}

// ---------------- attention precompute: collapse the prev-dependent path ------
__global__ __launch_bounds__(128) void k_pre(const float* __restrict__ lin_W,
                                             const float* __restrict__ lin_b,
                                             const float* __restrict__ W1,
                                             const float* __restrict__ b1,
                                             const float* __restrict__ dec_W,
                                             float* __restrict__ attc) {
    int j = threadIdx.x;
    float c1 = 0.f, c0 = 0.f;
    for (int h = 0; h < H; ++h) {
        c1 += lin_W[h] * W1[h * HID + j];
        c0 += lin_b[h] * W1[h * HID + j];
    }
    attc[j] = c1;
    attc[HID + j] = c0 + b1[j];
    if (j == 0) {
        float e1 = 0.f, e0 = 0.f;
        for (int h = 0; h < H; ++h) { e1 += lin_W[h] * dec_W[h]; e0 += lin_b[h] * dec_W[h]; }
        attc[2 * HID] = e1;
        attc[2 * HID + 1] = e0;
    }
}

// ---------------- gather + conv + leaky (all 4 t), one wave per dst ------------
// No block barriers: agg is per-wave (wave-lockstep + compiler lgkmcnt).
__global__ __launch_bounds__(256) void k_gather(
    const float* __restrict__ x, const int* __restrict__ esrc,
    const int* __restrict__ offs, const int* __restrict__ cnt_dst,
    const float* __restrict__ rs_out, const float* __restrict__ rs_in,
    const float* __restrict__ conv_W, const float* __restrict__ conv_b,
    float* __restrict__ space1) {
    const int wave = threadIdx.x >> 6, lane = threadIdx.x & 63;
    const int dst = blockIdx.x * 4 + wave;   // grid exact: N_DST/4
    const int t_l = lane >> 4;
    const int h0 = (lane & 15) << 2;
    __shared__ float agg[4][4][H];           // [wave][t][h] — proven conflict-free
    float sp0 = 0.f, sp1 = 0.f, sp2 = 0.f, sp3 = 0.f;
    const float4* x4 = (const float4*)x;     // x row = 64 float4 (t = c>>4, h = (c&15)*4+i)

    for (int tt = 0; tt < 4; ++tt) {
        const int off = offs[tt * N_DST + dst];
        const int n = cnt_dst[tt * N_DST + dst];
        const int* ep = esrc + tt * NE + off;
        const float* rso = rs_out + tt * N_HP;
        float4 a0 = make_float4(0.f, 0.f, 0.f, 0.f);
        float4 a1 = make_float4(0.f, 0.f, 0.f, 0.f);
        float4 a2 = make_float4(0.f, 0.f, 0.f, 0.f);
        float4 a3 = make_float4(0.f, 0.f, 0.f, 0.f);
        int e = 0;
        for (; e + 8 <= n; e += 8) {   // 8 rows in flight
            int s0 = ep[e],     s1 = ep[e + 1], s2 = ep[e + 2], s3 = ep[e + 3];
            int s4 = ep[e + 4], s5 = ep[e + 5], s6 = ep[e + 6], s7 = ep[e + 7];
            float r0 = rso[s0], r1 = rso[s1], r2 = rso[s2], r3 = rso[s3];
            float r4 = rso[s4], r5 = rso[s5], r6 = rso[s6], r7 = rso[s7];
            float4 v0 = x4[s0 * 64 + lane];
            float4 v1 = x4[s1 * 64 + lane];
            float4 v2 = x4[s2 * 64 + lane];
            float4 v3 = x4[s3 * 64 + lane];
            float4 v4 = x4[s4 * 64 + lane];
            float4 v5 = x4[s5 * 64 + lane];
            float4 v6 = x4[s6 * 64 + lane];
            float4 v7 = x4[s7 * 64 + lane];
            a0.x += v0.x * r0; a0.y += v0.y * r0; a0.z += v0.z * r0; a0.w += v0.w * r0;
            a1.x += v1.x * r1; a1.y += v1.y * r1; a1.z += v1.z * r1; a1.w += v1.w * r1;
            a2.x += v2.x * r2; a2.y += v2.y * r2; a2.z += v2.z * r2; a2.w += v2.w * r2;
            a3.x += v3.x * r3; a3.y += v3.y * r3; a3.z += v3.z * r3; a3.w += v3.w * r3;
            a0.x += v4.x * r4; a0.y += v4.y * r4; a0.z += v4.z * r4; a0.w += v4.w * r4;
            a1.x += v5.x * r5; a1.y += v5.y * r5; a1.z += v5.z * r5; a1.w += v5.w * r5;
            a2.x += v6.x * r6; a2.y += v6.y * r6; a2.z += v6.z * r6; a2.w += v6.w * r6;
            a3.x += v7.x * r7; a3.y += v7.y * r7; a3.z += v7.z * r7; a3.w += v7.w * r7;
        }
        for (; e + 2 <= n; e += 2) {
            int s0 = ep[e], s1 = ep[e + 1];
            float r0 = rso[s0], r1 = rso[s1];
            float4 v0 = x4[s0 * 64 + lane];
            float4 v1 = x4[s1 * 64 + lane];
            a0.x += v0.x * r0; a0.y += v0.y * r0; a0.z += v0.z * r0; a0.w += v0.w * r0;
            a1.x += v1.x * r1; a1.y += v1.y * r1; a1.z += v1.z * r1; a1.w += v1.w * r1;
        }
        if (e < n) {
            int s0 = ep[e];
            float r0 = rso[s0];
            float4 v0 = x4[s0 * 64 + lane];
            a0.x += v0.x * r0; a0.y += v0.y * r0; a0.z += v0.z * r0; a0.w += v0.w * r0;
        }
        float ri = rs_in[tt * N_DST + dst];
        float4 acc = make_float4((a0.x + a1.x + a2.x + a3.x) * ri,
                                 (a0.y + a1.y + a2.y + a3.y) * ri,
                                 (a0.z + a1.z + a2.z + a3.z) * ri,
                                 (a0.w + a1.w + a2.w + a3.w) * ri);
        *(float4*)&agg[wave][t_l][h0] = acc;   // contiguous 1KB/wave: 0 conflicts
        const float* W = conv_W + tt * H * H;
        float m0 = 0.f, m1 = 0.f, m2 = 0.f, m3 = 0.f;
#pragma unroll
        for (int hc = 0; hc < H; hc += 4) {
            float4 q0 = *(const float4*)&agg[wave][0][hc];   // broadcast reads
            float4 q1 = *(const float4*)&agg[wave][1][hc];
            float4 q2 = *(const float4*)&agg[wave][2][hc];
            float4 q3 = *(const float4*)&agg[wave][3][hc];
            float w0 = W[(hc + 0) * H + lane];
            float w1 = W[(hc + 1) * H + lane];
            float w2 = W[(hc + 2) * H + lane];
            float w3 = W[(hc + 3) * H + lane];
            m0 += q0.x * w0 + q0.y * w1 + q0.z * w2 + q0.w * w3;
            m1 += q1.x * w0 + q1.y * w1 + q1.z * w2 + q1.w * w3;
            m2 += q2.x * w0 + q2.y * w1 + q2.z * w2 + q2.w * w3;
            m3 += q3.x * w0 + q3.y * w1 + q3.z * w2 + q3.w * w3;
        }
        float b = conv_b[tt * H + lane];
        m0 += b; m1 += b; m2 += b; m3 += b;
        sp0 += m0 > 0.f ? m0 : 0.01f * m0;
        sp1 += m1 > 0.f ? m1 : 0.01f * m1;
        sp2 += m2 > 0.f ? m2 : 0.01f * m2;
        sp3 += m3 > 0.f ? m3 : 0.01f * m3;
    }
    space1[(0 * N_DST + dst) * H + lane] = sp0;
    space1[(1 * N_DST + dst) * H + lane] = sp1;
    space1[(2 * N_DST + dst) * H + lane] = sp2;
    space1[(3 * N_DST + dst) * H + lane] = sp3;
}

// ---------------- attention + decode: round-2-proven structure ----------------
// 1 node per wave, 8 waves/block. All scalars except spt[4] in a small fully
// unrolled t-loop (this exact shape measured 44 VGPR / no spill in round 2).
__global__ __launch_bounds__(512) void k_att(
    const float* __restrict__ sp, const float* __restrict__ prev0,
    const float* __restrict__ W1, const float* __restrict__ b1,
    const float* __restrict__ W2, const float* __restrict__ b2,
    const float* __restrict__ dec_W, const float* __restrict__ dec_b,
    const float* __restrict__ attc,
    float* __restrict__ out) {
    __shared__ float sW1[H * HID];        // 32 KB, [h][j]
    __shared__ float sb[8][H];            // per-wave s1 broadcast
    const int wave = threadIdx.x >> 6, lane = threadIdx.x & 63;
    const int node = blockIdx.x * 8 + wave;   // grid exact: N_DST/8 = 6250
    for (int i = threadIdx.x; i < H * HID; i += 512) sW1[i] = W1[i];
    __syncthreads();   // only block-wide barrier

    const float b1a = b1[lane], b1b = b1[lane + 64];
    const float w2a = W2[lane], w2b = W2[lane + 64];
    const float c1a = attc[lane], c1b = attc[lane + 64];
    const float c0a = attc[HID + lane], c0b = attc[HID + lane + 64];
    const float e1s = attc[2 * HID], e0s = attc[2 * HID + 1];
    const float decw = dec_W[lane];
    const float b2s = b2[0], decb = dec_b[0];

    float prev = prev0[node];
    float spt[4];
#pragma unroll
    for (int t = 0; t < 4; ++t)
        spt[t] = sp[((size_t)t * N_DST + node) * H + lane];   // coalesced 256B

#pragma unroll
    for (int t = 0; t < 4; ++t) {
        float s1v = spt[t];
        sb[wave][lane] = s1v;      // per-wave broadcast (lockstep, no barrier)
        float d0 = 0.f, d1 = 0.f;
#pragma unroll 8
        for (int h = 0; h < H; ++h) {
            float s = sb[wave][h];
            d0 += s * sW1[h * HID + lane];
            d1 += s * sW1[h * HID + lane + 64];
        }
        float p0 = tanhf(d0 + b1a) * w2a + tanhf(d1 + b1b) * w2b;
        float p1 = tanhf(prev * c1a + c0a) * w2a + tanhf(prev * c1b + c0b) * w2b;
        float p2 = s1v * decw;
        for (int o = 32; o; o >>= 1) {
            p0 += __shfl_xor(p0, o);
            p1 += __shfl_xor(p1, o);
            p2 += __shfl_xor(p2, o);
        }
        float l0 = p0 + b2s, l1 = p1 + b2s;
        float mx = fmaxf(l0, l1);
        float ea = expf(l0 - mx), eb = expf(l1 - mx);
        float inv = 1.f / (ea + eb);
        float s2d = prev * e1s + e0s;              // s2 . dec_W scalar fn of prev
        float ov = (ea * p2 + eb * s2d) * inv + decb;
        prev = ov;
        if (lane == 0) out[(size_t)t * N_DST + node] = ov;
    }
}

extern "C" void kernel_launch(void* const* d_in, const int* in_sizes, int n_in,
                              void* d_out, int out_size, void* d_ws, size_t ws_size,
                              hipStream_t stream) {
    const float* x      = (const float*)d_in[0];
    const float* prev0  = (const float*)d_in[1];
    const float* conv_W = (const float*)d_in[2];
    const float* conv_b = (const float*)d_in[3];
    const float* lin_W  = (const float*)d_in[4];
    const float* lin_b  = (const float*)d_in[5];
    const float* att_W1 = (const float*)d_in[6];
    const float* att_b1 = (const float*)d_in[7];
    const float* att_W2 = (const float*)d_in[8];
    const float* att_b2 = (const float*)d_in[9];
    const float* dec_W  = (const float*)d_in[10];
    const float* dec_b  = (const float*)d_in[11];
    const int* src_idx  = (const int*)d_in[12];
    const int* dst_idx  = (const int*)d_in[13];
    float* out = (float*)d_out;

    char* p = (char*)d_ws;
    auto alloc = [&](size_t bytes) {
        char* q = p;
        p += (bytes + 255) & ~(size_t)255;
        return q;
    };
    int*   cnt_src = (int*)alloc((size_t)4 * N_HP * 4);
    int*   cnt_dst = (int*)alloc((size_t)4 * N_DST * 4);
    int*   offs    = (int*)alloc((size_t)4 * N_DST * 4);
    float* rs_out  = (float*)alloc((size_t)4 * N_HP * 4);
    float* rs_in   = (float*)alloc((size_t)4 * N_DST * 4);
    int*   pos     = (int*)alloc((size_t)4 * NE * 4);
    int*   esrc    = (int*)alloc((size_t)4 * NE * 4);
    int*   part    = (int*)alloc((size_t)NPART * 4);
    float* attc    = (float*)alloc((size_t)(2 * HID + 2) * 4);
    float* space1  = (float*)alloc((size_t)4 * N_DST * H * 4);

    // zero cnt_src + cnt_dst (contiguous, 256-aligned sizes)
    hipMemsetAsync(cnt_src, 0, (size_t)((char*)offs - (char*)cnt_src), stream);

    k_hist<<<(NE + 255) / 256, 256, 0, stream>>>(src_idx, dst_idx, cnt_src, cnt_dst, pos);
    k_rsout<<<(4 * N_HP + 255) / 256, 256, 0, stream>>>(cnt_src, rs_out);
    k_scanA<<<NPART, 256, 0, stream>>>(cnt_dst, part);
    k_scanB<<<1, 256, 0, stream>>>(part);
    k_scanC<<<NPART, 256, 0, stream>>>(cnt_dst, part, offs, rs_in);
    k_fill<<<(NE + 255) / 256, 256, 0, stream>>>(src_idx, dst_idx, pos, offs, esrc);
    k_pre<<<1, 128, 0, stream>>>(lin_W, lin_b, att_W1, att_b1, dec_W, attc);
    k_gather<<<N_DST / 4, 256, 0, stream>>>(x, esrc, offs, cnt_dst, rs_out, rs_in,
                                            conv_W, conv_b, space1);
    k_att<<<N_DST / 8, 512, 0, stream>>>(space1, prev0,
                                         att_W1, att_b1, att_W2, att_b2,
                                         dec_W, dec_b, attc, out);
}